// Round 1
// baseline (996.421 us; speedup 1.0000x reference)
//
#include <hip/hip_runtime.h>
#include <hip/hip_bf16.h>
#include <math.h>

#define HEADS 3
#define HO 384
#define NGRAPH 64
#define F_IN 256
#define SLOPE 0.2f

// ---- monotone float<->uint encoding for atomicMax on signed floats ----
__device__ __forceinline__ unsigned enc_f(float f) {
    unsigned u = __float_as_uint(f);
    return (u & 0x80000000u) ? ~u : (u | 0x80000000u);
}
__device__ __forceinline__ float dec_f(unsigned k) {
    unsigned u = (k & 0x80000000u) ? (k & 0x7fffffffu) : ~k;
    return __uint_as_float(u);
}

// ---- K1: fp32 GEMM h = x @ W  (M x 256) * (256 x 384) ----
#define BM 64
#define BN 64
#define BK 16
__global__ __launch_bounds__(256) void gemm_f32(const float* __restrict__ X,
                                                const float* __restrict__ W,
                                                float* __restrict__ H, int M) {
    __shared__ float As[BK][BM + 1];
    __shared__ float Bs[BK][BN];
    int t = threadIdx.x;
    int row0 = blockIdx.x * BM;
    int col0 = blockIdx.y * BN;
    int tm4 = (t >> 4) * 4;
    int tn4 = (t & 15) * 4;
    int a_kk = t & 15, a_r = t >> 4;
    int b_col = t & 63, b_k = t >> 6;
    float acc[4][4] = {};
    for (int k0 = 0; k0 < F_IN; k0 += BK) {
#pragma unroll
        for (int i = 0; i < 4; i++) {
            int r = row0 + a_r + 16 * i;
            As[a_kk][a_r + 16 * i] = (r < M) ? X[(size_t)r * F_IN + k0 + a_kk] : 0.f;
        }
#pragma unroll
        for (int i = 0; i < 4; i++) {
            Bs[b_k + 4 * i][b_col] = W[(size_t)(k0 + b_k + 4 * i) * HO + col0 + b_col];
        }
        __syncthreads();
#pragma unroll
        for (int k = 0; k < BK; k++) {
            float a[4], b[4];
#pragma unroll
            for (int i = 0; i < 4; i++) a[i] = As[k][tm4 + i];
#pragma unroll
            for (int j = 0; j < 4; j++) b[j] = Bs[k][tn4 + j];
#pragma unroll
            for (int i = 0; i < 4; i++)
#pragma unroll
                for (int j = 0; j < 4; j++) acc[i][j] += a[i] * b[j];
        }
        __syncthreads();
    }
#pragma unroll
    for (int i = 0; i < 4; i++) {
        int r = row0 + tm4 + i;
        if (r < M) {
            float4 v = make_float4(acc[i][0], acc[i][1], acc[i][2], acc[i][3]);
            *(float4*)(&H[(size_t)r * HO + col0 + tn4]) = v;
        }
    }
}

// ---- K2: per-node attention dots a_src[n,h], a_dst[n,h] (one wave/node) ----
__global__ __launch_bounds__(256) void att_k(const float* __restrict__ H,
                                             const float* __restrict__ att_src,
                                             const float* __restrict__ att_dst,
                                             float* __restrict__ a_src,
                                             float* __restrict__ a_dst, int N) {
    int wave = threadIdx.x >> 6;
    int lane = threadIdx.x & 63;
    int node = blockIdx.x * 4 + wave;
    if (node >= N) return;
    const float* hrow = H + (size_t)node * HO;
    float s[3] = {0.f, 0.f, 0.f}, dd[3] = {0.f, 0.f, 0.f};
#pragma unroll
    for (int k = 0; k < 6; k++) {
        int c = lane + 64 * k;          // head = k>>1 (64-blocks align inside 128-wide heads)
        float hv = hrow[c];
        s[k >> 1] += hv * att_src[c];
        dd[k >> 1] += hv * att_dst[c];
    }
#pragma unroll
    for (int i = 0; i < 3; i++) {
        float vs = s[i], vd = dd[i];
#pragma unroll
        for (int off = 32; off > 0; off >>= 1) {
            vs += __shfl_down(vs, off);
            vd += __shfl_down(vd, off);
        }
        if (lane == 0) {
            a_src[node * 3 + i] = vs;
            a_dst[node * 3 + i] = vd;
        }
    }
}

// ---- K3: edge pass 1: degree count + segment max (encoded atomicMax) ----
__global__ __launch_bounds__(256) void edge_p1(const int* __restrict__ ei,
                                               const float* __restrict__ a_src,
                                               const float* __restrict__ a_dst,
                                               unsigned* __restrict__ emax,
                                               int* __restrict__ count, int E, int N) {
    int e = blockIdx.x * 256 + threadIdx.x;
    int ET = E + N;
    if (e >= ET) return;
    int s, d;
    if (e < E) { s = ei[e]; d = ei[E + e]; } else { s = e - E; d = s; }
    atomicAdd(&count[d], 1);
#pragma unroll
    for (int hh = 0; hh < 3; hh++) {
        float v = a_src[s * 3 + hh] + a_dst[d * 3 + hh];
        v = (v > 0.f) ? v : SLOPE * v;
        atomicMax(&emax[d * 3 + hh], enc_f(v));
    }
}

// ---- K4a/b/c: exclusive scan of count[] -> offsets[], cursor[] ----
__global__ __launch_bounds__(256) void scan_a(const int* __restrict__ count,
                                              int* __restrict__ offsets,
                                              int* __restrict__ bsums, int N) {
    __shared__ int tmp[256];
    int t = threadIdx.x;
    int i = blockIdx.x * 256 + t;
    int v = (i < N) ? count[i] : 0;
    tmp[t] = v;
    __syncthreads();
    for (int off = 1; off < 256; off <<= 1) {
        int x = (t >= off) ? tmp[t - off] : 0;
        __syncthreads();
        tmp[t] += x;
        __syncthreads();
    }
    if (i < N) offsets[i] = tmp[t] - v;
    if (t == 255) bsums[blockIdx.x] = tmp[255];
}

__global__ __launch_bounds__(256) void scan_b(int* __restrict__ bsums, int NB) {
    __shared__ int tmp[256];
    int t = threadIdx.x;
    int v = (t < NB) ? bsums[t] : 0;
    tmp[t] = v;
    __syncthreads();
    for (int off = 1; off < 256; off <<= 1) {
        int x = (t >= off) ? tmp[t - off] : 0;
        __syncthreads();
        tmp[t] += x;
        __syncthreads();
    }
    if (t < NB) bsums[t] = tmp[t] - v;
}

__global__ __launch_bounds__(256) void scan_c(int* __restrict__ offsets,
                                              const int* __restrict__ bsums,
                                              int* __restrict__ cursor, int N) {
    int i = blockIdx.x * 256 + threadIdx.x;
    if (i < N) {
        int o = offsets[i] + bsums[blockIdx.x];
        offsets[i] = o;
        cursor[i] = o;
    }
}

// ---- K5: edge pass 2: exp, denom, scatter CSR record (src, ex0..2) ----
__global__ __launch_bounds__(256) void edge_p2(const int* __restrict__ ei,
                                               const float* __restrict__ a_src,
                                               const float* __restrict__ a_dst,
                                               const unsigned* __restrict__ emax,
                                               float* __restrict__ denom,
                                               int* __restrict__ cursor,
                                               uint4* __restrict__ csr, int E, int N) {
    int e = blockIdx.x * 256 + threadIdx.x;
    int ET = E + N;
    if (e >= ET) return;
    int s, d;
    if (e < E) { s = ei[e]; d = ei[E + e]; } else { s = e - E; d = s; }
    float ex[3];
#pragma unroll
    for (int hh = 0; hh < 3; hh++) {
        float v = a_src[s * 3 + hh] + a_dst[d * 3 + hh];
        v = (v > 0.f) ? v : SLOPE * v;
        float m = dec_f(emax[d * 3 + hh]);
        ex[hh] = expf(v - m);
        atomicAdd(&denom[d * 3 + hh], ex[hh]);
    }
    int pos = atomicAdd(&cursor[d], 1);
    csr[pos] = make_uint4((unsigned)s, __float_as_uint(ex[0]),
                          __float_as_uint(ex[1]), __float_as_uint(ex[2]));
}

// ---- K6: per-graph node counts via binary search on sorted batch ----
__global__ void graph_counts_k(const int* __restrict__ batch, int N,
                               int* __restrict__ gcount) {
    int g = threadIdx.x;
    if (g >= NGRAPH) return;
    int lo = 0, hi = N;
    while (lo < hi) { int mid = (lo + hi) >> 1; if (batch[mid] < g) lo = mid + 1; else hi = mid; }
    int lb = lo;
    lo = 0; hi = N;
    while (lo < hi) { int mid = (lo + hi) >> 1; if (batch[mid] <= g) lo = mid + 1; else hi = mid; }
    gcount[g] = lo - lb;
}

// ---- K7: aggregation (one block per dst node) + relu+bias + pooled atomics ----
__global__ __launch_bounds__(384) void aggregate_k(const float* __restrict__ H,
                                                   const uint4* __restrict__ csr,
                                                   const int* __restrict__ offsets,
                                                   const int* __restrict__ count,
                                                   const float* __restrict__ denom,
                                                   const float* __restrict__ bias,
                                                   const int* __restrict__ batch,
                                                   float* __restrict__ pooled, int N) {
    int d = blockIdx.x;
    int t = threadIdx.x;       // channel 0..383
    int head = t >> 7;         // wave-uniform
    int start = offsets[d];
    int n = count[d];
    float inv = 1.0f / (denom[d * 3 + head] + 1e-16f);
    float acc = 0.0f;
    for (int i = 0; i < n; i++) {
        uint4 rec = csr[start + i];
        int s = (int)rec.x;
        unsigned exb = (head == 0) ? rec.y : ((head == 1) ? rec.z : rec.w);
        acc += __uint_as_float(exb) * H[(size_t)s * HO + t];
    }
    float v = acc * inv + bias[t];
    v = (v > 0.f) ? v : 0.f;
    atomicAdd(&pooled[batch[d] * HO + t], v);
}

// ---- K8: FC over pooled means ----
__global__ __launch_bounds__(64) void fc_k(const float* __restrict__ pooled,
                                           const int* __restrict__ gcount,
                                           const float* __restrict__ fc_w,
                                           const float* __restrict__ fc_b,
                                           float* __restrict__ out) {
    int g = blockIdx.x;
    int lane = threadIdx.x;
    float a0 = 0.f, a1 = 0.f;
#pragma unroll
    for (int k = 0; k < 6; k++) {
        int c = lane + 64 * k;
        float pv = pooled[g * HO + c];
        a0 += pv * fc_w[c * 2 + 0];
        a1 += pv * fc_w[c * 2 + 1];
    }
#pragma unroll
    for (int off = 32; off > 0; off >>= 1) {
        a0 += __shfl_down(a0, off);
        a1 += __shfl_down(a1, off);
    }
    if (lane == 0) {
        float cnt = fmaxf((float)gcount[g], 1.0f);
        out[g * 2 + 0] = a0 / cnt + fc_b[0];
        out[g * 2 + 1] = a1 / cnt + fc_b[1];
    }
}

extern "C" void kernel_launch(void* const* d_in, const int* in_sizes, int n_in,
                              void* d_out, int out_size, void* d_ws, size_t ws_size,
                              hipStream_t stream) {
    const float* x       = (const float*)d_in[0];
    const int*   ei      = (const int*)d_in[1];
    const int*   batch   = (const int*)d_in[2];
    const float* W       = (const float*)d_in[3];
    const float* att_src = (const float*)d_in[4];
    const float* att_dst = (const float*)d_in[5];
    const float* bias    = (const float*)d_in[6];
    const float* fc_w    = (const float*)d_in[7];
    const float* fc_b    = (const float*)d_in[8];
    float* out = (float*)d_out;

    const int N = in_sizes[2];
    const int E = in_sizes[1] / 2;
    const int ET = E + N;

    // bump allocator over d_ws, 256B-aligned chunks (total ~93 MB)
    char* p = (char*)d_ws;
    auto alloc = [&](size_t bytes) -> char* {
        char* r = p;
        p += (bytes + 255) & ~(size_t)255;
        return r;
    };
    float*    h      = (float*)alloc((size_t)N * HO * 4);      // 76.8 MB
    float*    a_src  = (float*)alloc((size_t)N * 3 * 4);
    float*    a_dst  = (float*)alloc((size_t)N * 3 * 4);
    char*     zstart = p;
    unsigned* emax   = (unsigned*)alloc((size_t)N * 3 * 4);    // zeroed (acts as -inf key)
    float*    denom  = (float*)alloc((size_t)N * 3 * 4);       // zeroed
    int*      count  = (int*)alloc((size_t)N * 4);             // zeroed
    float*    pooled = (float*)alloc((size_t)NGRAPH * HO * 4); // zeroed
    size_t    zbytes = (size_t)(p - zstart);
    int*      offsets = (int*)alloc((size_t)N * 4);
    int*      cursor  = (int*)alloc((size_t)N * 4);
    int*      bsums   = (int*)alloc(4096);
    int*      gcount  = (int*)alloc(1024);
    uint4*    csr     = (uint4*)alloc((size_t)ET * 16);        // 13.6 MB

    hipMemsetAsync(zstart, 0, zbytes, stream);

    dim3 gg((N + BM - 1) / BM, HO / BN);
    gemm_f32<<<gg, 256, 0, stream>>>(x, W, h, N);
    att_k<<<(N + 3) / 4, 256, 0, stream>>>(h, att_src, att_dst, a_src, a_dst, N);
    edge_p1<<<(ET + 255) / 256, 256, 0, stream>>>(ei, a_src, a_dst, emax, count, E, N);
    int NB = (N + 255) / 256;   // 196 <= 256
    scan_a<<<NB, 256, 0, stream>>>(count, offsets, bsums, N);
    scan_b<<<1, 256, 0, stream>>>(bsums, NB);
    scan_c<<<NB, 256, 0, stream>>>(offsets, bsums, cursor, N);
    edge_p2<<<(ET + 255) / 256, 256, 0, stream>>>(ei, a_src, a_dst, emax, denom, cursor, csr, E, N);
    graph_counts_k<<<1, 64, 0, stream>>>(batch, N, gcount);
    aggregate_k<<<N, 384, 0, stream>>>(h, csr, offsets, count, denom, bias, batch, pooled, N);
    fc_k<<<NGRAPH, 64, 0, stream>>>(pooled, gcount, fc_w, fc_b, out);

    (void)n_in; (void)out_size; (void)ws_size;
}

// Round 3
// 796.618 us; speedup vs baseline: 1.2508x; 1.2508x over previous
//
#include <hip/hip_runtime.h>
#include <hip/hip_bf16.h>
#include <math.h>

#define HEADS 3
#define HO 384
#define NGRAPH 64
#define F_IN 256
#define SLOPE 0.2f

typedef __attribute__((ext_vector_type(8))) short bf8;
typedef __attribute__((ext_vector_type(4))) float f4;

// ---- helpers ----
__device__ __forceinline__ unsigned enc_f(float f) {
    unsigned u = __float_as_uint(f);
    return (u & 0x80000000u) ? ~u : (u | 0x80000000u);
}
__device__ __forceinline__ float dec_f(unsigned k) {
    unsigned u = (k & 0x80000000u) ? (k & 0x7fffffffu) : ~k;
    return __uint_as_float(u);
}
// fp32 -> bf16 (round to nearest even), as raw ushort
__device__ __forceinline__ unsigned short bfr(float f) {
    unsigned u = __float_as_uint(f);
    u += 0x7fffu + ((u >> 16) & 1u);
    return (unsigned short)(u >> 16);
}
__device__ __forceinline__ float bflo(unsigned u) { return __uint_as_float(u << 16); }
__device__ __forceinline__ float bfhi(unsigned u) { return __uint_as_float(u & 0xffff0000u); }

// ---- K0a: convert x (fp32) -> xb (bf16 packed) ----
__global__ __launch_bounds__(256) void conv_x(const float4* __restrict__ X,
                                              uint2* __restrict__ O, int n4) {
    int i = blockIdx.x * 256 + threadIdx.x;
    if (i < n4) {
        float4 v = X[i];
        O[i] = make_uint2((unsigned)bfr(v.x) | ((unsigned)bfr(v.y) << 16),
                          (unsigned)bfr(v.z) | ((unsigned)bfr(v.w) << 16));
    }
}

// ---- K0b: convert W (fp32 [256,384]) -> WbT (bf16 [384,256]) ----
__global__ __launch_bounds__(256) void conv_wT(const float* __restrict__ W,
                                               short* __restrict__ WbT) {
    int n = blockIdx.x;   // 0..383
    int k = threadIdx.x;  // 0..255
    WbT[n * 256 + k] = (short)bfr(W[(size_t)k * HO + n]);
}

// ---- K1: bf16 MFMA GEMM  Hb = xb @ W  (stored packed bf16, [N,384]) ----
// block = 256 threads (4 waves). Block tile: 64 rows x 384 cols.
// wave w: row-pair = w>>1 (32 rows via 2 A-tiles), colHalf = w&1 (192 cols via 12 tiles).
// NOTE round-2 bug: tile claimed 128 rows but waves only covered 64 -> half of Hb
// was 0xAA poison. Grid is now (N+63)/64 with a true 64-row tile.
__global__ __launch_bounds__(256) void gemm_mfma(const short* __restrict__ Xb,
                                                 const short* __restrict__ WbT,
                                                 unsigned* __restrict__ Hb, int N) {
    int w = threadIdx.x >> 6, lane = threadIdx.x & 63;
    int quad = lane >> 4, l15 = lane & 15;
    int rbase = blockIdx.x * 64 + (w >> 1) * 32;
    int cbase = (w & 1) * 192;
    f4 acc[2][12] = {};
    int arow0 = rbase + l15;
    int arow1 = rbase + 16 + l15;
    arow0 = (arow0 < N) ? arow0 : (N - 1);   // clamp: garbage rows never stored
    arow1 = (arow1 < N) ? arow1 : (N - 1);
    for (int k0 = 0; k0 < F_IN; k0 += 32) {
        int ko = k0 + quad * 8;
        bf8 a0 = *(const bf8*)(Xb + (size_t)arow0 * F_IN + ko);
        bf8 a1 = *(const bf8*)(Xb + (size_t)arow1 * F_IN + ko);
#pragma unroll
        for (int nt = 0; nt < 12; nt++) {
            int ncol = cbase + nt * 16 + l15;
            bf8 b = *(const bf8*)(WbT + (size_t)ncol * F_IN + ko);
            acc[0][nt] = __builtin_amdgcn_mfma_f32_16x16x32_bf16(a0, b, acc[0][nt], 0, 0, 0);
            acc[1][nt] = __builtin_amdgcn_mfma_f32_16x16x32_bf16(a1, b, acc[1][nt], 0, 0, 0);
        }
    }
    // C/D layout: col = lane&15, row(within 16-tile) = quad*4 + reg
#pragma unroll
    for (int at = 0; at < 2; at++) {
#pragma unroll
        for (int nt = 0; nt < 12; nt++) {
#pragma unroll
            for (int r = 0; r < 4; r++) {
                float v = acc[at][nt][r];
                float vp = __shfl_xor(v, 1);   // partner col c^1, same row
                int node = rbase + at * 16 + quad * 4 + r;
                if (!(lane & 1) && node < N) {
                    unsigned pk = (unsigned)bfr(v) | ((unsigned)bfr(vp) << 16);
                    Hb[(size_t)node * 192 + (cbase >> 1) + nt * 8 + (l15 >> 1)] = pk;
                }
            }
        }
    }
}

// ---- K2: per-node attention dots from bf16 h (one wave per node) ----
__global__ __launch_bounds__(256) void att_k(const unsigned* __restrict__ Hb,
                                             const float* __restrict__ att_src,
                                             const float* __restrict__ att_dst,
                                             float* __restrict__ a_src,
                                             float* __restrict__ a_dst, int N) {
    int wave = threadIdx.x >> 6;
    int lane = threadIdx.x & 63;
    int node = blockIdx.x * 4 + wave;
    if (node >= N) return;
    const unsigned* hrow = Hb + (size_t)node * 192;
#pragma unroll
    for (int hd = 0; hd < 3; hd++) {
        unsigned u = hrow[hd * 64 + lane];
        float lo = bflo(u), hi = bfhi(u);
        int c = hd * 128 + 2 * lane;
        float vs = lo * att_src[c] + hi * att_src[c + 1];
        float vd = lo * att_dst[c] + hi * att_dst[c + 1];
#pragma unroll
        for (int off = 32; off > 0; off >>= 1) {
            vs += __shfl_down(vs, off);
            vd += __shfl_down(vd, off);
        }
        if (lane == 0) {
            a_src[node * 3 + hd] = vs;
            a_dst[node * 3 + hd] = vd;
        }
    }
}

// ---- K3: edge pass 1: degree count + segment max (encoded atomicMax) ----
__global__ __launch_bounds__(256) void edge_p1(const int* __restrict__ ei,
                                               const float* __restrict__ a_src,
                                               const float* __restrict__ a_dst,
                                               unsigned* __restrict__ emax,
                                               int* __restrict__ count, int E, int N) {
    int e = blockIdx.x * 256 + threadIdx.x;
    int ET = E + N;
    if (e >= ET) return;
    int s, d;
    if (e < E) { s = ei[e]; d = ei[E + e]; } else { s = e - E; d = s; }
    atomicAdd(&count[d], 1);
#pragma unroll
    for (int hh = 0; hh < 3; hh++) {
        float v = a_src[s * 3 + hh] + a_dst[d * 3 + hh];
        v = (v > 0.f) ? v : SLOPE * v;
        atomicMax(&emax[d * 3 + hh], enc_f(v));
    }
}

// ---- K4a/b/c: exclusive scan of count[] -> offsets[], cursor[] ----
__global__ __launch_bounds__(256) void scan_a(const int* __restrict__ count,
                                              int* __restrict__ offsets,
                                              int* __restrict__ bsums, int N) {
    __shared__ int tmp[256];
    int t = threadIdx.x;
    int i = blockIdx.x * 256 + t;
    int v = (i < N) ? count[i] : 0;
    tmp[t] = v;
    __syncthreads();
    for (int off = 1; off < 256; off <<= 1) {
        int x = (t >= off) ? tmp[t - off] : 0;
        __syncthreads();
        tmp[t] += x;
        __syncthreads();
    }
    if (i < N) offsets[i] = tmp[t] - v;
    if (t == 255) bsums[blockIdx.x] = tmp[255];
}

__global__ __launch_bounds__(256) void scan_b(int* __restrict__ bsums, int NB) {
    __shared__ int tmp[256];
    int t = threadIdx.x;
    int v = (t < NB) ? bsums[t] : 0;
    tmp[t] = v;
    __syncthreads();
    for (int off = 1; off < 256; off <<= 1) {
        int x = (t >= off) ? tmp[t - off] : 0;
        __syncthreads();
        tmp[t] += x;
        __syncthreads();
    }
    if (t < NB) bsums[t] = tmp[t] - v;
}

__global__ __launch_bounds__(256) void scan_c(int* __restrict__ offsets,
                                              const int* __restrict__ bsums,
                                              int* __restrict__ cursor, int N) {
    int i = blockIdx.x * 256 + threadIdx.x;
    if (i < N) {
        int o = offsets[i] + bsums[blockIdx.x];
        offsets[i] = o;
        cursor[i] = o;
    }
}

// ---- K5: edge pass 2: exp, denom, scatter CSR record (src, ex0..2) ----
__global__ __launch_bounds__(256) void edge_p2(const int* __restrict__ ei,
                                               const float* __restrict__ a_src,
                                               const float* __restrict__ a_dst,
                                               const unsigned* __restrict__ emax,
                                               float* __restrict__ denom,
                                               int* __restrict__ cursor,
                                               uint4* __restrict__ csr, int E, int N) {
    int e = blockIdx.x * 256 + threadIdx.x;
    int ET = E + N;
    if (e >= ET) return;
    int s, d;
    if (e < E) { s = ei[e]; d = ei[E + e]; } else { s = e - E; d = s; }
    float ex[3];
#pragma unroll
    for (int hh = 0; hh < 3; hh++) {
        float v = a_src[s * 3 + hh] + a_dst[d * 3 + hh];
        v = (v > 0.f) ? v : SLOPE * v;
        float m = dec_f(emax[d * 3 + hh]);
        ex[hh] = expf(v - m);
        atomicAdd(&denom[d * 3 + hh], ex[hh]);
    }
    int pos = atomicAdd(&cursor[d], 1);
    csr[pos] = make_uint4((unsigned)s, __float_as_uint(ex[0]),
                          __float_as_uint(ex[1]), __float_as_uint(ex[2]));
}

// ---- K6: per-graph node counts via binary search on sorted batch ----
__global__ void graph_counts_k(const int* __restrict__ batch, int N,
                               int* __restrict__ gcount) {
    int g = threadIdx.x;
    if (g >= NGRAPH) return;
    int lo = 0, hi = N;
    while (lo < hi) { int mid = (lo + hi) >> 1; if (batch[mid] < g) lo = mid + 1; else hi = mid; }
    int lb = lo;
    lo = 0; hi = N;
    while (lo < hi) { int mid = (lo + hi) >> 1; if (batch[mid] <= g) lo = mid + 1; else hi = mid; }
    gcount[g] = lo - lb;
}

// ---- K7: aggregation over bf16 h (one 192-thr block per dst), unroll x4 ----
// thread t owns channels (2t, 2t+1); head = t>>6 (wave-uniform).
__global__ __launch_bounds__(192) void aggregate_k(const unsigned* __restrict__ Hb,
                                                   const uint4* __restrict__ csr,
                                                   const int* __restrict__ offsets,
                                                   const int* __restrict__ count,
                                                   const float* __restrict__ denom,
                                                   const float* __restrict__ bias,
                                                   const int* __restrict__ batch,
                                                   float* __restrict__ pooled, int N) {
    int d = blockIdx.x;
    int t = threadIdx.x;
    int head = t >> 6;
    int start = offsets[d];
    int n = count[d];
    float inv = 1.0f / (denom[d * 3 + head] + 1e-16f);
    const uint4* ep = csr + start;
    float a0 = 0.f, a1 = 0.f;
    int i = 0;
    for (; i + 4 <= n; i += 4) {
        uint4 r0 = ep[i], r1 = ep[i + 1], r2 = ep[i + 2], r3 = ep[i + 3];
        unsigned u0 = Hb[(size_t)r0.x * 192 + t];
        unsigned u1 = Hb[(size_t)r1.x * 192 + t];
        unsigned u2 = Hb[(size_t)r2.x * 192 + t];
        unsigned u3 = Hb[(size_t)r3.x * 192 + t];
        float e0 = __uint_as_float(head == 0 ? r0.y : (head == 1 ? r0.z : r0.w));
        float e1 = __uint_as_float(head == 0 ? r1.y : (head == 1 ? r1.z : r1.w));
        float e2 = __uint_as_float(head == 0 ? r2.y : (head == 1 ? r2.z : r2.w));
        float e3 = __uint_as_float(head == 0 ? r3.y : (head == 1 ? r3.z : r3.w));
        a0 += e0 * bflo(u0) + e1 * bflo(u1) + e2 * bflo(u2) + e3 * bflo(u3);
        a1 += e0 * bfhi(u0) + e1 * bfhi(u1) + e2 * bfhi(u2) + e3 * bfhi(u3);
    }
    for (; i < n; i++) {
        uint4 r = ep[i];
        unsigned u = Hb[(size_t)r.x * 192 + t];
        float e = __uint_as_float(head == 0 ? r.y : (head == 1 ? r.z : r.w));
        a0 += e * bflo(u);
        a1 += e * bfhi(u);
    }
    int c0 = 2 * t;
    float v0 = a0 * inv + bias[c0];
    float v1 = a1 * inv + bias[c0 + 1];
    v0 = (v0 > 0.f) ? v0 : 0.f;
    v1 = (v1 > 0.f) ? v1 : 0.f;
    int g = batch[d];
    atomicAdd(&pooled[g * HO + c0], v0);
    atomicAdd(&pooled[g * HO + c0 + 1], v1);
}

// ---- K8: FC over pooled means ----
__global__ __launch_bounds__(64) void fc_k(const float* __restrict__ pooled,
                                           const int* __restrict__ gcount,
                                           const float* __restrict__ fc_w,
                                           const float* __restrict__ fc_b,
                                           float* __restrict__ out) {
    int g = blockIdx.x;
    int lane = threadIdx.x;
    float a0 = 0.f, a1 = 0.f;
#pragma unroll
    for (int k = 0; k < 6; k++) {
        int c = lane + 64 * k;
        float pv = pooled[g * HO + c];
        a0 += pv * fc_w[c * 2 + 0];
        a1 += pv * fc_w[c * 2 + 1];
    }
#pragma unroll
    for (int off = 32; off > 0; off >>= 1) {
        a0 += __shfl_down(a0, off);
        a1 += __shfl_down(a1, off);
    }
    if (lane == 0) {
        float cnt = fmaxf((float)gcount[g], 1.0f);
        out[g * 2 + 0] = a0 / cnt + fc_b[0];
        out[g * 2 + 1] = a1 / cnt + fc_b[1];
    }
}

extern "C" void kernel_launch(void* const* d_in, const int* in_sizes, int n_in,
                              void* d_out, int out_size, void* d_ws, size_t ws_size,
                              hipStream_t stream) {
    const float* x       = (const float*)d_in[0];
    const int*   ei      = (const int*)d_in[1];
    const int*   batch   = (const int*)d_in[2];
    const float* W       = (const float*)d_in[3];
    const float* att_src = (const float*)d_in[4];
    const float* att_dst = (const float*)d_in[5];
    const float* bias    = (const float*)d_in[6];
    const float* fc_w    = (const float*)d_in[7];
    const float* fc_b    = (const float*)d_in[8];
    float* out = (float*)d_out;

    const int N = in_sizes[2];
    const int E = in_sizes[1] / 2;
    const int ET = E + N;
    const int XE = in_sizes[0];   // N * 256

    // bump allocator over d_ws (total ~80 MB)
    char* p = (char*)d_ws;
    auto alloc = [&](size_t bytes) -> char* {
        char* r = p;
        p += (bytes + 255) & ~(size_t)255;
        return r;
    };
    short*    xb     = (short*)alloc((size_t)XE * 2);           // 25.6 MB bf16 x
    short*    wbt    = (short*)alloc((size_t)HO * F_IN * 2);    // 192 KB bf16 W^T
    unsigned* hb     = (unsigned*)alloc((size_t)N * 192 * 4);   // 38.4 MB bf16 h (packed)
    float*    a_src  = (float*)alloc((size_t)N * 3 * 4);
    float*    a_dst  = (float*)alloc((size_t)N * 3 * 4);
    char*     zstart = p;
    unsigned* emax   = (unsigned*)alloc((size_t)N * 3 * 4);     // zeroed (acts as -inf key)
    float*    denom  = (float*)alloc((size_t)N * 3 * 4);        // zeroed
    int*      count  = (int*)alloc((size_t)N * 4);              // zeroed
    float*    pooled = (float*)alloc((size_t)NGRAPH * HO * 4);  // zeroed
    size_t    zbytes = (size_t)(p - zstart);
    int*      offsets = (int*)alloc((size_t)N * 4);
    int*      cursor  = (int*)alloc((size_t)N * 4);
    int*      bsums   = (int*)alloc(4096);
    int*      gcount  = (int*)alloc(1024);
    uint4*    csr     = (uint4*)alloc((size_t)ET * 16);         // 13.6 MB

    hipMemsetAsync(zstart, 0, zbytes, stream);

    int n4 = XE / 4;
    conv_x<<<(n4 + 255) / 256, 256, 0, stream>>>((const float4*)x, (uint2*)xb, n4);
    conv_wT<<<HO, 256, 0, stream>>>(W, wbt);
    gemm_mfma<<<(N + 63) / 64, 256, 0, stream>>>(xb, wbt, hb, N);
    att_k<<<(N + 3) / 4, 256, 0, stream>>>(hb, att_src, att_dst, a_src, a_dst, N);
    edge_p1<<<(ET + 255) / 256, 256, 0, stream>>>(ei, a_src, a_dst, emax, count, E, N);
    int NB = (N + 255) / 256;
    scan_a<<<NB, 256, 0, stream>>>(count, offsets, bsums, N);
    scan_b<<<1, 256, 0, stream>>>(bsums, NB);
    scan_c<<<NB, 256, 0, stream>>>(offsets, bsums, cursor, N);
    edge_p2<<<(ET + 255) / 256, 256, 0, stream>>>(ei, a_src, a_dst, emax, denom, cursor, csr, E, N);
    graph_counts_k<<<1, 64, 0, stream>>>(batch, N, gcount);
    aggregate_k<<<N, 192, 0, stream>>>(hb, csr, offsets, count, denom, bias, batch, pooled, N);
    fc_k<<<NGRAPH, 64, 0, stream>>>(pooled, gcount, fc_w, fc_b, out);

    (void)n_in; (void)out_size; (void)ws_size;
}

// Round 4
// 454.050 us; speedup vs baseline: 2.1945x; 1.7545x over previous
//
#include <hip/hip_runtime.h>
#include <hip/hip_bf16.h>
#include <math.h>

#define HEADS 3
#define HO 384
#define NGRAPH 64
#define F_IN 256
#define SLOPE 0.2f

typedef __attribute__((ext_vector_type(8))) short bf8;
typedef __attribute__((ext_vector_type(4))) float f4;

// ---- bf16 helpers ----
__device__ __forceinline__ unsigned short bfr(float f) {
    unsigned u = __float_as_uint(f);
    u += 0x7fffu + ((u >> 16) & 1u);
    return (unsigned short)(u >> 16);
}
__device__ __forceinline__ float bflo(unsigned u) { return __uint_as_float(u << 16); }
__device__ __forceinline__ float bfhi(unsigned u) { return __uint_as_float(u & 0xffff0000u); }
__device__ __forceinline__ float lrelu(float v) { return (v > 0.f) ? v : SLOPE * v; }

// ---- K0a: convert x (fp32) -> xb (bf16 packed) ----
__global__ __launch_bounds__(256) void conv_x(const float4* __restrict__ X,
                                              uint2* __restrict__ O, int n4) {
    int i = blockIdx.x * 256 + threadIdx.x;
    if (i < n4) {
        float4 v = X[i];
        O[i] = make_uint2((unsigned)bfr(v.x) | ((unsigned)bfr(v.y) << 16),
                          (unsigned)bfr(v.z) | ((unsigned)bfr(v.w) << 16));
    }
}

// ---- K0b: convert W (fp32 [256,384]) -> WbT (bf16 [384,256]) ----
__global__ __launch_bounds__(256) void conv_wT(const float* __restrict__ W,
                                               short* __restrict__ WbT) {
    int n = blockIdx.x;
    int k = threadIdx.x;
    WbT[n * 256 + k] = (short)bfr(W[(size_t)k * HO + n]);
}

// ---- K1: bf16 MFMA GEMM Hb = xb @ W (packed bf16 [N,192 words]) ----
// 64-row x 384-col block tile; wave pair (w>>1) = 32 rows, colHalf (w&1) = 192 cols.
__global__ __launch_bounds__(256) void gemm_mfma(const short* __restrict__ Xb,
                                                 const short* __restrict__ WbT,
                                                 unsigned* __restrict__ Hb, int N) {
    int w = threadIdx.x >> 6, lane = threadIdx.x & 63;
    int quad = lane >> 4, l15 = lane & 15;
    int rbase = blockIdx.x * 64 + (w >> 1) * 32;
    int cbase = (w & 1) * 192;
    f4 acc[2][12] = {};
    int arow0 = rbase + l15;
    int arow1 = rbase + 16 + l15;
    arow0 = (arow0 < N) ? arow0 : (N - 1);
    arow1 = (arow1 < N) ? arow1 : (N - 1);
    for (int k0 = 0; k0 < F_IN; k0 += 32) {
        int ko = k0 + quad * 8;
        bf8 a0 = *(const bf8*)(Xb + (size_t)arow0 * F_IN + ko);
        bf8 a1 = *(const bf8*)(Xb + (size_t)arow1 * F_IN + ko);
#pragma unroll
        for (int nt = 0; nt < 12; nt++) {
            int ncol = cbase + nt * 16 + l15;
            bf8 b = *(const bf8*)(WbT + (size_t)ncol * F_IN + ko);
            acc[0][nt] = __builtin_amdgcn_mfma_f32_16x16x32_bf16(a0, b, acc[0][nt], 0, 0, 0);
            acc[1][nt] = __builtin_amdgcn_mfma_f32_16x16x32_bf16(a1, b, acc[1][nt], 0, 0, 0);
        }
    }
    // C/D layout: col = lane&15, row(within tile) = quad*4 + reg
#pragma unroll
    for (int at = 0; at < 2; at++) {
#pragma unroll
        for (int nt = 0; nt < 12; nt++) {
#pragma unroll
            for (int r = 0; r < 4; r++) {
                float v = acc[at][nt][r];
                float vp = __shfl_xor(v, 1);
                int node = rbase + at * 16 + quad * 4 + r;
                if (!(lane & 1) && node < N) {
                    unsigned pk = (unsigned)bfr(v) | ((unsigned)bfr(vp) << 16);
                    Hb[(size_t)node * 192 + (cbase >> 1) + nt * 8 + (l15 >> 1)] = pk;
                }
            }
        }
    }
}

// ---- K2: per-node attention dots (one wave per node) ----
__global__ __launch_bounds__(256) void att_k(const unsigned* __restrict__ Hb,
                                             const float* __restrict__ att_src,
                                             const float* __restrict__ att_dst,
                                             float* __restrict__ a_src,
                                             float* __restrict__ a_dst, int N) {
    int wave = threadIdx.x >> 6;
    int lane = threadIdx.x & 63;
    int node = blockIdx.x * 4 + wave;
    if (node >= N) return;
    const unsigned* hrow = Hb + (size_t)node * 192;
#pragma unroll
    for (int hd = 0; hd < 3; hd++) {
        unsigned u = hrow[hd * 64 + lane];
        float lo = bflo(u), hi = bfhi(u);
        int c = hd * 128 + 2 * lane;
        float vs = lo * att_src[c] + hi * att_src[c + 1];
        float vd = lo * att_dst[c] + hi * att_dst[c + 1];
#pragma unroll
        for (int off = 32; off > 0; off >>= 1) {
            vs += __shfl_down(vs, off);
            vd += __shfl_down(vd, off);
        }
        if (lane == 0) {
            a_src[node * 3 + hd] = vs;
            a_dst[node * 3 + hd] = vd;
        }
    }
}

// ---- K3: degree count (1 atomic/edge) ----
__global__ __launch_bounds__(256) void count_k(const int* __restrict__ ei,
                                               int* __restrict__ count, int E, int N) {
    int e = blockIdx.x * 256 + threadIdx.x;
    int ET = E + N;
    if (e >= ET) return;
    int d = (e < E) ? ei[E + e] : (e - E);
    atomicAdd(&count[d], 1);
}

// ---- K4a/b/c: exclusive scan of count[] -> offsets[], cursor[] ----
__global__ __launch_bounds__(256) void scan_a(const int* __restrict__ count,
                                              int* __restrict__ offsets,
                                              int* __restrict__ bsums, int N) {
    __shared__ int tmp[256];
    int t = threadIdx.x;
    int i = blockIdx.x * 256 + t;
    int v = (i < N) ? count[i] : 0;
    tmp[t] = v;
    __syncthreads();
    for (int off = 1; off < 256; off <<= 1) {
        int x = (t >= off) ? tmp[t - off] : 0;
        __syncthreads();
        tmp[t] += x;
        __syncthreads();
    }
    if (i < N) offsets[i] = tmp[t] - v;
    if (t == 255) bsums[blockIdx.x] = tmp[255];
}

__global__ __launch_bounds__(256) void scan_b(int* __restrict__ bsums, int NB) {
    __shared__ int tmp[256];
    int t = threadIdx.x;
    int v = (t < NB) ? bsums[t] : 0;
    tmp[t] = v;
    __syncthreads();
    for (int off = 1; off < 256; off <<= 1) {
        int x = (t >= off) ? tmp[t - off] : 0;
        __syncthreads();
        tmp[t] += x;
        __syncthreads();
    }
    if (t < NB) bsums[t] = tmp[t] - v;
}

__global__ __launch_bounds__(256) void scan_c(int* __restrict__ offsets,
                                              const int* __restrict__ bsums,
                                              int* __restrict__ cursor, int N) {
    int i = blockIdx.x * 256 + threadIdx.x;
    if (i < N) {
        int o = offsets[i] + bsums[blockIdx.x];
        offsets[i] = o;
        cursor[i] = o;
    }
}

// ---- K5: scatter src into CSR (sorted by dst) ----
__global__ __launch_bounds__(256) void scatter_k(const int* __restrict__ ei,
                                                 int* __restrict__ cursor,
                                                 uint4* __restrict__ csr, int E, int N) {
    int e = blockIdx.x * 256 + threadIdx.x;
    int ET = E + N;
    if (e >= ET) return;
    int s, d;
    if (e < E) { s = ei[e]; d = ei[E + e]; } else { s = e - E; d = s; }
    int pos = atomicAdd(&cursor[d], 1);
    csr[pos] = make_uint4((unsigned)s, 0u, 0u, 0u);
}

// ---- K6: per-dst softmax (one wave per dst) -> alpha into csr.yzw ----
__global__ __launch_bounds__(256) void softmax_k(uint4* __restrict__ csr,
                                                 const int* __restrict__ offsets,
                                                 const int* __restrict__ count,
                                                 const float* __restrict__ a_src,
                                                 const float* __restrict__ a_dst, int N) {
    int wid = blockIdx.x * 4 + (threadIdx.x >> 6);
    int lane = threadIdx.x & 63;
    if (wid >= N) return;
    int start = offsets[wid], n = count[wid];
    float ad0 = a_dst[wid * 3 + 0], ad1 = a_dst[wid * 3 + 1], ad2 = a_dst[wid * 3 + 2];
    if (n <= 64) {   // the (overwhelmingly) common path: one edge per lane
        float l0 = -INFINITY, l1 = -INFINITY, l2 = -INFINITY;
        unsigned s = 0;
        if (lane < n) {
            s = csr[start + lane].x;
            l0 = lrelu(a_src[s * 3 + 0] + ad0);
            l1 = lrelu(a_src[s * 3 + 1] + ad1);
            l2 = lrelu(a_src[s * 3 + 2] + ad2);
        }
        float m0 = l0, m1 = l1, m2 = l2;
#pragma unroll
        for (int off = 1; off < 64; off <<= 1) {
            m0 = fmaxf(m0, __shfl_xor(m0, off));
            m1 = fmaxf(m1, __shfl_xor(m1, off));
            m2 = fmaxf(m2, __shfl_xor(m2, off));
        }
        float e0 = (lane < n) ? expf(l0 - m0) : 0.f;
        float e1 = (lane < n) ? expf(l1 - m1) : 0.f;
        float e2 = (lane < n) ? expf(l2 - m2) : 0.f;
        float s0 = e0, s1 = e1, s2 = e2;
#pragma unroll
        for (int off = 1; off < 64; off <<= 1) {
            s0 += __shfl_xor(s0, off);
            s1 += __shfl_xor(s1, off);
            s2 += __shfl_xor(s2, off);
        }
        float i0 = 1.f / (s0 + 1e-16f), i1 = 1.f / (s1 + 1e-16f), i2 = 1.f / (s2 + 1e-16f);
        if (lane < n)
            csr[start + lane] = make_uint4(s, __float_as_uint(e0 * i0),
                                           __float_as_uint(e1 * i1), __float_as_uint(e2 * i2));
    } else {         // rare high-degree fallback
        float m0 = -INFINITY, m1 = -INFINITY, m2 = -INFINITY;
        for (int j = lane; j < n; j += 64) {
            unsigned s = csr[start + j].x;
            m0 = fmaxf(m0, lrelu(a_src[s * 3 + 0] + ad0));
            m1 = fmaxf(m1, lrelu(a_src[s * 3 + 1] + ad1));
            m2 = fmaxf(m2, lrelu(a_src[s * 3 + 2] + ad2));
        }
#pragma unroll
        for (int off = 1; off < 64; off <<= 1) {
            m0 = fmaxf(m0, __shfl_xor(m0, off));
            m1 = fmaxf(m1, __shfl_xor(m1, off));
            m2 = fmaxf(m2, __shfl_xor(m2, off));
        }
        float s0 = 0.f, s1 = 0.f, s2 = 0.f;
        for (int j = lane; j < n; j += 64) {
            unsigned s = csr[start + j].x;
            s0 += expf(lrelu(a_src[s * 3 + 0] + ad0) - m0);
            s1 += expf(lrelu(a_src[s * 3 + 1] + ad1) - m1);
            s2 += expf(lrelu(a_src[s * 3 + 2] + ad2) - m2);
        }
#pragma unroll
        for (int off = 1; off < 64; off <<= 1) {
            s0 += __shfl_xor(s0, off);
            s1 += __shfl_xor(s1, off);
            s2 += __shfl_xor(s2, off);
        }
        float i0 = 1.f / (s0 + 1e-16f), i1 = 1.f / (s1 + 1e-16f), i2 = 1.f / (s2 + 1e-16f);
        for (int j = lane; j < n; j += 64) {
            unsigned s = csr[start + j].x;
            float a0 = expf(lrelu(a_src[s * 3 + 0] + ad0) - m0) * i0;
            float a1 = expf(lrelu(a_src[s * 3 + 1] + ad1) - m1) * i1;
            float a2 = expf(lrelu(a_src[s * 3 + 2] + ad2) - m2) * i2;
            csr[start + j] = make_uint4(s, __float_as_uint(a0),
                                        __float_as_uint(a1), __float_as_uint(a2));
        }
    }
}

// ---- K7: graph starts via binary search (batch sorted) ----
__global__ void graph_starts_k(const int* __restrict__ batch, int N,
                               int* __restrict__ gstart) {
    int g = threadIdx.x;
    if (g > NGRAPH) return;
    int lo = 0, hi = N;
    while (lo < hi) { int mid = (lo + hi) >> 1; if (batch[mid] < g) lo = mid + 1; else hi = mid; }
    gstart[g] = lo;
}

// ---- K8: aggregation, one wave per dst. lane covers words {lane,64+lane,128+lane}
//      (one word per head). Unroll x4 -> 12 gathers + 4 record loads in flight.
//      Writes relu(out+bias) as packed bf16 [N,192] — no atomics. ----
__global__ __launch_bounds__(256) void aggregate_k(const unsigned* __restrict__ Hb,
                                                   const uint4* __restrict__ csr,
                                                   const int* __restrict__ offsets,
                                                   const int* __restrict__ count,
                                                   const float* __restrict__ bias,
                                                   unsigned* __restrict__ outb, int N) {
    int wid = blockIdx.x * 4 + (threadIdx.x >> 6);
    int lane = threadIdx.x & 63;
    if (wid >= N) return;
    int start = offsets[wid], n = count[wid];
    const uint4* ep = csr + start;
    float a0l = 0.f, a0h = 0.f, a1l = 0.f, a1h = 0.f, a2l = 0.f, a2h = 0.f;
    int i = 0;
    for (; i + 4 <= n; i += 4) {
        uint4 r0 = ep[i], r1 = ep[i + 1], r2 = ep[i + 2], r3 = ep[i + 3];
        const unsigned* h0 = Hb + (size_t)r0.x * 192;
        const unsigned* h1 = Hb + (size_t)r1.x * 192;
        const unsigned* h2 = Hb + (size_t)r2.x * 192;
        const unsigned* h3 = Hb + (size_t)r3.x * 192;
        unsigned u00 = h0[lane], u01 = h0[lane + 64], u02 = h0[lane + 128];
        unsigned u10 = h1[lane], u11 = h1[lane + 64], u12 = h1[lane + 128];
        unsigned u20 = h2[lane], u21 = h2[lane + 64], u22 = h2[lane + 128];
        unsigned u30 = h3[lane], u31 = h3[lane + 64], u32 = h3[lane + 128];
        float w00 = __uint_as_float(r0.y), w01 = __uint_as_float(r0.z), w02 = __uint_as_float(r0.w);
        float w10 = __uint_as_float(r1.y), w11 = __uint_as_float(r1.z), w12 = __uint_as_float(r1.w);
        float w20 = __uint_as_float(r2.y), w21 = __uint_as_float(r2.z), w22 = __uint_as_float(r2.w);
        float w30 = __uint_as_float(r3.y), w31 = __uint_as_float(r3.z), w32 = __uint_as_float(r3.w);
        a0l += w00 * bflo(u00) + w10 * bflo(u10) + w20 * bflo(u20) + w30 * bflo(u30);
        a0h += w00 * bfhi(u00) + w10 * bfhi(u10) + w20 * bfhi(u20) + w30 * bfhi(u30);
        a1l += w01 * bflo(u01) + w11 * bflo(u11) + w21 * bflo(u21) + w31 * bflo(u31);
        a1h += w01 * bfhi(u01) + w11 * bfhi(u11) + w21 * bfhi(u21) + w31 * bfhi(u31);
        a2l += w02 * bflo(u02) + w12 * bflo(u12) + w22 * bflo(u22) + w32 * bflo(u32);
        a2h += w02 * bfhi(u02) + w12 * bfhi(u12) + w22 * bfhi(u22) + w32 * bfhi(u32);
    }
    for (; i < n; i++) {
        uint4 r = ep[i];
        const unsigned* h = Hb + (size_t)r.x * 192;
        unsigned u0 = h[lane], u1 = h[lane + 64], u2 = h[lane + 128];
        float w0 = __uint_as_float(r.y), w1 = __uint_as_float(r.z), w2 = __uint_as_float(r.w);
        a0l += w0 * bflo(u0); a0h += w0 * bfhi(u0);
        a1l += w1 * bflo(u1); a1h += w1 * bfhi(u1);
        a2l += w2 * bflo(u2); a2h += w2 * bfhi(u2);
    }
    // relu(acc + bias) -> packed bf16; word w holds channels (2w, 2w+1)
    unsigned* orow = outb + (size_t)wid * 192;
    int c0 = 2 * lane;
    float v;
    float b0 = bias[c0], b1 = bias[c0 + 1];
    float b2 = bias[128 + c0], b3 = bias[128 + c0 + 1];
    float b4 = bias[256 + c0], b5 = bias[256 + c0 + 1];
    unsigned pk;
    v = a0l + b0; float x0 = (v > 0.f) ? v : 0.f;
    v = a0h + b1; float x1 = (v > 0.f) ? v : 0.f;
    pk = (unsigned)bfr(x0) | ((unsigned)bfr(x1) << 16);
    orow[lane] = pk;
    v = a1l + b2; x0 = (v > 0.f) ? v : 0.f;
    v = a1h + b3; x1 = (v > 0.f) ? v : 0.f;
    pk = (unsigned)bfr(x0) | ((unsigned)bfr(x1) << 16);
    orow[64 + lane] = pk;
    v = a2l + b4; x0 = (v > 0.f) ? v : 0.f;
    v = a2h + b5; x1 = (v > 0.f) ? v : 0.f;
    pk = (unsigned)bfr(x0) | ((unsigned)bfr(x1) << 16);
    orow[128 + lane] = pk;
}

// ---- K9: segment-sum pool over contiguous per-graph row ranges ----
__global__ __launch_bounds__(192) void pool_k(const unsigned* __restrict__ outb,
                                              const int* __restrict__ gstart,
                                              float* __restrict__ pooled) {
    int g = blockIdx.x;
    int chunk = blockIdx.y;         // 0..7
    int t = threadIdx.x;            // word 0..191
    int lo = gstart[g], hi = gstart[g + 1];
    float al = 0.f, ah = 0.f;
    for (int r = lo + chunk; r < hi; r += 8) {
        unsigned u = outb[(size_t)r * 192 + t];
        al += bflo(u);
        ah += bfhi(u);
    }
    atomicAdd(&pooled[g * HO + 2 * t], al);
    atomicAdd(&pooled[g * HO + 2 * t + 1], ah);
}

// ---- K10: FC over pooled means ----
__global__ __launch_bounds__(64) void fc_k(const float* __restrict__ pooled,
                                           const int* __restrict__ gstart,
                                           const float* __restrict__ fc_w,
                                           const float* __restrict__ fc_b,
                                           float* __restrict__ out) {
    int g = blockIdx.x;
    int lane = threadIdx.x;
    float a0 = 0.f, a1 = 0.f;
#pragma unroll
    for (int k = 0; k < 6; k++) {
        int c = lane + 64 * k;
        float pv = pooled[g * HO + c];
        a0 += pv * fc_w[c * 2 + 0];
        a1 += pv * fc_w[c * 2 + 1];
    }
#pragma unroll
    for (int off = 32; off > 0; off >>= 1) {
        a0 += __shfl_down(a0, off);
        a1 += __shfl_down(a1, off);
    }
    if (lane == 0) {
        float cnt = fmaxf((float)(gstart[g + 1] - gstart[g]), 1.0f);
        out[g * 2 + 0] = a0 / cnt + fc_b[0];
        out[g * 2 + 1] = a1 / cnt + fc_b[1];
    }
}

extern "C" void kernel_launch(void* const* d_in, const int* in_sizes, int n_in,
                              void* d_out, int out_size, void* d_ws, size_t ws_size,
                              hipStream_t stream) {
    const float* x       = (const float*)d_in[0];
    const int*   ei      = (const int*)d_in[1];
    const int*   batch   = (const int*)d_in[2];
    const float* W       = (const float*)d_in[3];
    const float* att_src = (const float*)d_in[4];
    const float* att_dst = (const float*)d_in[5];
    const float* bias    = (const float*)d_in[6];
    const float* fc_w    = (const float*)d_in[7];
    const float* fc_b    = (const float*)d_in[8];
    float* out = (float*)d_out;

    const int N = in_sizes[2];
    const int E = in_sizes[1] / 2;
    const int ET = E + N;
    const int XE = in_sizes[0];

    // bump allocator over d_ws (total ~118 MB)
    char* p = (char*)d_ws;
    auto alloc = [&](size_t bytes) -> char* {
        char* r = p;
        p += (bytes + 255) & ~(size_t)255;
        return r;
    };
    short*    xb     = (short*)alloc((size_t)XE * 2);           // 25.6 MB
    short*    wbt    = (short*)alloc((size_t)HO * F_IN * 2);    // 192 KB
    unsigned* hb     = (unsigned*)alloc((size_t)N * 192 * 4);   // 38.4 MB
    unsigned* outb   = (unsigned*)alloc((size_t)N * 192 * 4);   // 38.4 MB bf16 relu'd out
    float*    a_src  = (float*)alloc((size_t)N * 3 * 4);
    float*    a_dst  = (float*)alloc((size_t)N * 3 * 4);
    char*     zstart = p;
    int*      count  = (int*)alloc((size_t)N * 4);              // zeroed
    float*    pooled = (float*)alloc((size_t)NGRAPH * HO * 4);  // zeroed
    size_t    zbytes = (size_t)(p - zstart);
    int*      offsets = (int*)alloc((size_t)N * 4);
    int*      cursor  = (int*)alloc((size_t)N * 4);
    int*      bsums   = (int*)alloc(4096);
    int*      gstart  = (int*)alloc(1024);
    uint4*    csr     = (uint4*)alloc((size_t)ET * 16);         // 13.6 MB

    hipMemsetAsync(zstart, 0, zbytes, stream);

    int n4 = XE / 4;
    conv_x<<<(n4 + 255) / 256, 256, 0, stream>>>((const float4*)x, (uint2*)xb, n4);
    conv_wT<<<HO, 256, 0, stream>>>(W, wbt);
    gemm_mfma<<<(N + 63) / 64, 256, 0, stream>>>(xb, wbt, hb, N);
    att_k<<<(N + 3) / 4, 256, 0, stream>>>(hb, att_src, att_dst, a_src, a_dst, N);
    count_k<<<(ET + 255) / 256, 256, 0, stream>>>(ei, count, E, N);
    int NB = (N + 255) / 256;
    scan_a<<<NB, 256, 0, stream>>>(count, offsets, bsums, N);
    scan_b<<<1, 256, 0, stream>>>(bsums, NB);
    scan_c<<<NB, 256, 0, stream>>>(offsets, bsums, cursor, N);
    scatter_k<<<(ET + 255) / 256, 256, 0, stream>>>(ei, cursor, csr, E, N);
    softmax_k<<<(N + 3) / 4, 256, 0, stream>>>(csr, offsets, count, a_src, a_dst, N);
    graph_starts_k<<<1, 128, 0, stream>>>(batch, N, gstart);
    aggregate_k<<<(N + 3) / 4, 256, 0, stream>>>(hb, csr, offsets, count, bias, outb, N);
    dim3 pg(NGRAPH, 8);
    pool_k<<<pg, 192, 0, stream>>>(outb, gstart, pooled);
    fc_k<<<NGRAPH, 64, 0, stream>>>(pooled, gstart, fc_w, fc_b, out);

    (void)n_in; (void)out_size; (void)ws_size;
}

// Round 5
// 421.715 us; speedup vs baseline: 2.3628x; 1.0767x over previous
//
#include <hip/hip_runtime.h>
#include <hip/hip_bf16.h>
#include <math.h>

#define HEADS 3
#define HO 384
#define NGRAPH 64
#define F_IN 256
#define SLOPE 0.2f

typedef __attribute__((ext_vector_type(8))) short bf8;
typedef __attribute__((ext_vector_type(4))) float f4;

// ---- bf16 helpers ----
__device__ __forceinline__ unsigned short bfr(float f) {
    unsigned u = __float_as_uint(f);
    u += 0x7fffu + ((u >> 16) & 1u);
    return (unsigned short)(u >> 16);
}
__device__ __forceinline__ float bflo(unsigned u) { return __uint_as_float(u << 16); }
__device__ __forceinline__ float bfhi(unsigned u) { return __uint_as_float(u & 0xffff0000u); }
__device__ __forceinline__ float lrelu(float v) { return (v > 0.f) ? v : SLOPE * v; }

// ---- K0: convert W (fp32 [256,384]) -> WbT (bf16 [384,256]) ----
__global__ __launch_bounds__(256) void conv_wT(const float* __restrict__ W,
                                               short* __restrict__ WbT) {
    int n = blockIdx.x;
    int k = threadIdx.x;
    WbT[n * 256 + k] = (short)bfr(W[(size_t)k * HO + n]);
}

// ---- K1: fused bf16 MFMA GEMM + attention dots.
// Reads x fp32 directly (cvt in-reg), writes packed-bf16 Hb [N,192 words] and
// fp32 a_src/a_dst [N,3] (computed from fp32 accumulators in the epilogue).
// Block tile 64 rows x 384 cols; wave (w>>1) = 32-row group, (w&1) = 192-col half.
__global__ __launch_bounds__(256) void gemm_att(const float* __restrict__ X,
                                                const short* __restrict__ WbT,
                                                const float* __restrict__ att_src,
                                                const float* __restrict__ att_dst,
                                                unsigned* __restrict__ Hb,
                                                float* __restrict__ aSrcO,
                                                float* __restrict__ aDstO, int N) {
    __shared__ float lsS[64][4];
    __shared__ float lsD[64][4];
    int w = threadIdx.x >> 6, lane = threadIdx.x & 63;
    int quad = lane >> 4, l15 = lane & 15;
    int rbase = blockIdx.x * 64 + (w >> 1) * 32;
    int cbase = (w & 1) * 192;
    f4 acc[2][12] = {};
    int arow0 = rbase + l15;
    int arow1 = rbase + 16 + l15;
    arow0 = (arow0 < N) ? arow0 : (N - 1);   // clamped rows are never stored
    arow1 = (arow1 < N) ? arow1 : (N - 1);
    for (int k0 = 0; k0 < F_IN; k0 += 32) {
        int ko = k0 + quad * 8;
        const float4* xr0 = (const float4*)(X + (size_t)arow0 * F_IN + ko);
        const float4* xr1 = (const float4*)(X + (size_t)arow1 * F_IN + ko);
        float4 p0 = xr0[0], p1 = xr0[1];
        float4 q0 = xr1[0], q1 = xr1[1];
        bf8 a0, a1;
        a0[0] = (short)bfr(p0.x); a0[1] = (short)bfr(p0.y);
        a0[2] = (short)bfr(p0.z); a0[3] = (short)bfr(p0.w);
        a0[4] = (short)bfr(p1.x); a0[5] = (short)bfr(p1.y);
        a0[6] = (short)bfr(p1.z); a0[7] = (short)bfr(p1.w);
        a1[0] = (short)bfr(q0.x); a1[1] = (short)bfr(q0.y);
        a1[2] = (short)bfr(q0.z); a1[3] = (short)bfr(q0.w);
        a1[4] = (short)bfr(q1.x); a1[5] = (short)bfr(q1.y);
        a1[6] = (short)bfr(q1.z); a1[7] = (short)bfr(q1.w);
#pragma unroll
        for (int nt = 0; nt < 12; nt++) {
            int ncol = cbase + nt * 16 + l15;
            bf8 b = *(const bf8*)(WbT + (size_t)ncol * F_IN + ko);
            acc[0][nt] = __builtin_amdgcn_mfma_f32_16x16x32_bf16(a0, b, acc[0][nt], 0, 0, 0);
            acc[1][nt] = __builtin_amdgcn_mfma_f32_16x16x32_bf16(a1, b, acc[1][nt], 0, 0, 0);
        }
    }
    // ---- attention-dot epilogue from fp32 acc ----
    // col of (nt, l15) = cbase + nt*16 + l15. Head split within this wave's half:
    // cbase=0:   nt<8 -> head0           ; nt>=8 -> head1(lo)   -> slots 0,1
    // cbase=192: nt<4 -> head1(hi)       ; nt>=4 -> head2       -> slots 2,3
    float asv[12], adv[12];
#pragma unroll
    for (int nt = 0; nt < 12; nt++) {
        int c = cbase + nt * 16 + l15;
        asv[nt] = att_src[c];
        adv[nt] = att_dst[c];
    }
    int split = (w & 1) ? 4 : 8;
#pragma unroll
    for (int at = 0; at < 2; at++) {
#pragma unroll
        for (int r = 0; r < 4; r++) {
            float paS = 0.f, pbS = 0.f, paD = 0.f, pbD = 0.f;
#pragma unroll
            for (int nt = 0; nt < 12; nt++) {
                float v = acc[at][nt][r];
                if (nt < split) { paS += v * asv[nt]; paD += v * adv[nt]; }
                else            { pbS += v * asv[nt]; pbD += v * adv[nt]; }
            }
#pragma unroll
            for (int off = 1; off < 16; off <<= 1) {
                paS += __shfl_xor(paS, off); pbS += __shfl_xor(pbS, off);
                paD += __shfl_xor(paD, off); pbD += __shfl_xor(pbD, off);
            }
            if (l15 == 0) {
                int row = (w >> 1) * 32 + at * 16 + quad * 4 + r;
                int sl = (w & 1) * 2;
                lsS[row][sl] = paS; lsS[row][sl + 1] = pbS;
                lsD[row][sl] = paD; lsD[row][sl + 1] = pbD;
            }
        }
    }
    // ---- Hb store (C/D layout: col = lane&15, row = quad*4 + reg) ----
#pragma unroll
    for (int at = 0; at < 2; at++) {
#pragma unroll
        for (int nt = 0; nt < 12; nt++) {
#pragma unroll
            for (int r = 0; r < 4; r++) {
                float v = acc[at][nt][r];
                float vp = __shfl_xor(v, 1);
                int node = rbase + at * 16 + quad * 4 + r;
                if (!(lane & 1) && node < N) {
                    unsigned pk = (unsigned)bfr(v) | ((unsigned)bfr(vp) << 16);
                    Hb[(size_t)node * 192 + (cbase >> 1) + nt * 8 + (l15 >> 1)] = pk;
                }
            }
        }
    }
    __syncthreads();
    int t = threadIdx.x;
    if (t < 64) {
        int node = blockIdx.x * 64 + t;
        if (node < N) {
            aSrcO[node * 3 + 0] = lsS[t][0];
            aSrcO[node * 3 + 1] = lsS[t][1] + lsS[t][2];
            aSrcO[node * 3 + 2] = lsS[t][3];
            aDstO[node * 3 + 0] = lsD[t][0];
            aDstO[node * 3 + 1] = lsD[t][1] + lsD[t][2];
            aDstO[node * 3 + 2] = lsD[t][3];
        }
    }
}

// ---- K2: degree count (1 atomic/edge) ----
__global__ __launch_bounds__(256) void count_k(const int* __restrict__ ei,
                                               int* __restrict__ count, int E, int N) {
    int e = blockIdx.x * 256 + threadIdx.x;
    int ET = E + N;
    if (e >= ET) return;
    int d = (e < E) ? ei[E + e] : (e - E);
    atomicAdd(&count[d], 1);
}

// ---- K3a/b/c: exclusive scan of count[] -> offsets[], cursor[] ----
__global__ __launch_bounds__(256) void scan_a(const int* __restrict__ count,
                                              int* __restrict__ offsets,
                                              int* __restrict__ bsums, int N) {
    __shared__ int tmp[256];
    int t = threadIdx.x;
    int i = blockIdx.x * 256 + t;
    int v = (i < N) ? count[i] : 0;
    tmp[t] = v;
    __syncthreads();
    for (int off = 1; off < 256; off <<= 1) {
        int x = (t >= off) ? tmp[t - off] : 0;
        __syncthreads();
        tmp[t] += x;
        __syncthreads();
    }
    if (i < N) offsets[i] = tmp[t] - v;
    if (t == 255) bsums[blockIdx.x] = tmp[255];
}

__global__ __launch_bounds__(256) void scan_b(int* __restrict__ bsums, int NB) {
    __shared__ int tmp[256];
    int t = threadIdx.x;
    int v = (t < NB) ? bsums[t] : 0;
    tmp[t] = v;
    __syncthreads();
    for (int off = 1; off < 256; off <<= 1) {
        int x = (t >= off) ? tmp[t - off] : 0;
        __syncthreads();
        tmp[t] += x;
        __syncthreads();
    }
    if (t < NB) bsums[t] = tmp[t] - v;
}

__global__ __launch_bounds__(256) void scan_c(int* __restrict__ offsets,
                                              const int* __restrict__ bsums,
                                              int* __restrict__ cursor, int N) {
    int i = blockIdx.x * 256 + threadIdx.x;
    if (i < N) {
        int o = offsets[i] + bsums[blockIdx.x];
        offsets[i] = o;
        cursor[i] = o;
    }
}

// ---- K4: scatter src index into CSR (4B records) ----
__global__ __launch_bounds__(256) void scatter_k(const int* __restrict__ ei,
                                                 int* __restrict__ cursor,
                                                 int* __restrict__ csr_src, int E, int N) {
    int e = blockIdx.x * 256 + threadIdx.x;
    int ET = E + N;
    if (e >= ET) return;
    int s, d;
    if (e < E) { s = ei[e]; d = ei[E + e]; } else { s = e - E; d = s; }
    int pos = atomicAdd(&cursor[d], 1);
    csr_src[pos] = s;
}

// ---- K5: graph starts via binary search (batch sorted) ----
__global__ void graph_starts_k(const int* __restrict__ batch, int N,
                               int* __restrict__ gstart) {
    int g = threadIdx.x;
    if (g > NGRAPH) return;
    int lo = 0, hi = N;
    while (lo < hi) { int mid = (lo + hi) >> 1; if (batch[mid] < g) lo = mid + 1; else hi = mid; }
    gstart[g] = lo;
}

// ---- K6: fused softmax + aggregation, one wave per dst.
// Softmax over <=64 in-edges in-register (one edge/lane, shuffle reductions);
// gather loop broadcasts (src, alpha0..2) from lane j via __shfl.
// Writes relu(out+bias) as packed bf16 [N,192] — no atomics. ----
__global__ __launch_bounds__(256) void aggregate_k(const unsigned* __restrict__ Hb,
                                                   const int* __restrict__ csr_src,
                                                   const int* __restrict__ offsets,
                                                   const int* __restrict__ count,
                                                   const float* __restrict__ a_src,
                                                   const float* __restrict__ a_dst,
                                                   const float* __restrict__ bias,
                                                   unsigned* __restrict__ outb, int N) {
    int wid = blockIdx.x * 4 + (threadIdx.x >> 6);
    int lane = threadIdx.x & 63;
    if (wid >= N) return;
    int start = offsets[wid], n = count[wid];
    float ad0 = a_dst[wid * 3 + 0], ad1 = a_dst[wid * 3 + 1], ad2 = a_dst[wid * 3 + 2];
    float a0l = 0.f, a0h = 0.f, a1l = 0.f, a1h = 0.f, a2l = 0.f, a2h = 0.f;

    if (n <= 64) {
        // ---- in-register softmax: one edge per lane ----
        int sreg = 0;
        float l0 = -INFINITY, l1 = -INFINITY, l2 = -INFINITY;
        if (lane < n) {
            sreg = csr_src[start + lane];
            l0 = lrelu(a_src[sreg * 3 + 0] + ad0);
            l1 = lrelu(a_src[sreg * 3 + 1] + ad1);
            l2 = lrelu(a_src[sreg * 3 + 2] + ad2);
        }
        float m0 = l0, m1 = l1, m2 = l2;
#pragma unroll
        for (int off = 1; off < 64; off <<= 1) {
            m0 = fmaxf(m0, __shfl_xor(m0, off));
            m1 = fmaxf(m1, __shfl_xor(m1, off));
            m2 = fmaxf(m2, __shfl_xor(m2, off));
        }
        float e0 = (lane < n) ? expf(l0 - m0) : 0.f;
        float e1 = (lane < n) ? expf(l1 - m1) : 0.f;
        float e2 = (lane < n) ? expf(l2 - m2) : 0.f;
        float s0 = e0, s1 = e1, s2 = e2;
#pragma unroll
        for (int off = 1; off < 64; off <<= 1) {
            s0 += __shfl_xor(s0, off);
            s1 += __shfl_xor(s1, off);
            s2 += __shfl_xor(s2, off);
        }
        float w0r = e0 / (s0 + 1e-16f);
        float w1r = e1 / (s1 + 1e-16f);
        float w2r = e2 / (s2 + 1e-16f);
        // ---- gather: broadcast edge j's (src, alphas) from lane j ----
        int j = 0;
        for (; j + 4 <= n; j += 4) {
            int i0 = __shfl(sreg, j), i1 = __shfl(sreg, j + 1);
            int i2 = __shfl(sreg, j + 2), i3 = __shfl(sreg, j + 3);
            const unsigned* h0 = Hb + (size_t)i0 * 192;
            const unsigned* h1 = Hb + (size_t)i1 * 192;
            const unsigned* h2 = Hb + (size_t)i2 * 192;
            const unsigned* h3 = Hb + (size_t)i3 * 192;
            unsigned u00 = h0[lane], u01 = h0[lane + 64], u02 = h0[lane + 128];
            unsigned u10 = h1[lane], u11 = h1[lane + 64], u12 = h1[lane + 128];
            unsigned u20 = h2[lane], u21 = h2[lane + 64], u22 = h2[lane + 128];
            unsigned u30 = h3[lane], u31 = h3[lane + 64], u32 = h3[lane + 128];
            float w00 = __shfl(w0r, j),     w01 = __shfl(w1r, j),     w02 = __shfl(w2r, j);
            float w10 = __shfl(w0r, j + 1), w11 = __shfl(w1r, j + 1), w12 = __shfl(w2r, j + 1);
            float w20 = __shfl(w0r, j + 2), w21 = __shfl(w1r, j + 2), w22 = __shfl(w2r, j + 2);
            float w30 = __shfl(w0r, j + 3), w31 = __shfl(w1r, j + 3), w32 = __shfl(w2r, j + 3);
            a0l += w00 * bflo(u00) + w10 * bflo(u10) + w20 * bflo(u20) + w30 * bflo(u30);
            a0h += w00 * bfhi(u00) + w10 * bfhi(u10) + w20 * bfhi(u20) + w30 * bfhi(u30);
            a1l += w01 * bflo(u01) + w11 * bflo(u11) + w21 * bflo(u21) + w31 * bflo(u31);
            a1h += w01 * bfhi(u01) + w11 * bfhi(u11) + w21 * bfhi(u21) + w31 * bfhi(u31);
            a2l += w02 * bflo(u02) + w12 * bflo(u12) + w22 * bflo(u22) + w32 * bflo(u32);
            a2h += w02 * bfhi(u02) + w12 * bfhi(u12) + w22 * bfhi(u22) + w32 * bfhi(u32);
        }
        for (; j < n; j++) {
            int si = __shfl(sreg, j);
            const unsigned* h = Hb + (size_t)si * 192;
            unsigned u0 = h[lane], u1 = h[lane + 64], u2 = h[lane + 128];
            float w0 = __shfl(w0r, j), w1 = __shfl(w1r, j), w2 = __shfl(w2r, j);
            a0l += w0 * bflo(u0); a0h += w0 * bfhi(u0);
            a1l += w1 * bflo(u1); a1h += w1 * bfhi(u1);
            a2l += w2 * bflo(u2); a2h += w2 * bfhi(u2);
        }
    } else {
        // ---- rare high-degree fallback (correctness only) ----
        float m0 = -INFINITY, m1 = -INFINITY, m2 = -INFINITY;
        for (int j = lane; j < n; j += 64) {
            int s = csr_src[start + j];
            m0 = fmaxf(m0, lrelu(a_src[s * 3 + 0] + ad0));
            m1 = fmaxf(m1, lrelu(a_src[s * 3 + 1] + ad1));
            m2 = fmaxf(m2, lrelu(a_src[s * 3 + 2] + ad2));
        }
#pragma unroll
        for (int off = 1; off < 64; off <<= 1) {
            m0 = fmaxf(m0, __shfl_xor(m0, off));
            m1 = fmaxf(m1, __shfl_xor(m1, off));
            m2 = fmaxf(m2, __shfl_xor(m2, off));
        }
        float s0 = 0.f, s1 = 0.f, s2 = 0.f;
        for (int j = lane; j < n; j += 64) {
            int s = csr_src[start + j];
            s0 += expf(lrelu(a_src[s * 3 + 0] + ad0) - m0);
            s1 += expf(lrelu(a_src[s * 3 + 1] + ad1) - m1);
            s2 += expf(lrelu(a_src[s * 3 + 2] + ad2) - m2);
        }
#pragma unroll
        for (int off = 1; off < 64; off <<= 1) {
            s0 += __shfl_xor(s0, off);
            s1 += __shfl_xor(s1, off);
            s2 += __shfl_xor(s2, off);
        }
        float i0 = 1.f / (s0 + 1e-16f), i1 = 1.f / (s1 + 1e-16f), i2 = 1.f / (s2 + 1e-16f);
        for (int j = 0; j < n; j++) {
            int s = csr_src[start + j];   // wave-uniform load
            float w0 = expf(lrelu(a_src[s * 3 + 0] + ad0) - m0) * i0;
            float w1 = expf(lrelu(a_src[s * 3 + 1] + ad1) - m1) * i1;
            float w2 = expf(lrelu(a_src[s * 3 + 2] + ad2) - m2) * i2;
            const unsigned* h = Hb + (size_t)s * 192;
            unsigned u0 = h[lane], u1 = h[lane + 64], u2 = h[lane + 128];
            a0l += w0 * bflo(u0); a0h += w0 * bfhi(u0);
            a1l += w1 * bflo(u1); a1h += w1 * bfhi(u1);
            a2l += w2 * bflo(u2); a2h += w2 * bfhi(u2);
        }
    }

    // relu(acc + bias) -> packed bf16; word w holds channels (2w, 2w+1)
    unsigned* orow = outb + (size_t)wid * 192;
    int c0 = 2 * lane;
    float b0 = bias[c0], b1 = bias[c0 + 1];
    float b2 = bias[128 + c0], b3 = bias[128 + c0 + 1];
    float b4 = bias[256 + c0], b5 = bias[256 + c0 + 1];
    float v, x0, x1;
    unsigned pk;
    v = a0l + b0; x0 = (v > 0.f) ? v : 0.f;
    v = a0h + b1; x1 = (v > 0.f) ? v : 0.f;
    pk = (unsigned)bfr(x0) | ((unsigned)bfr(x1) << 16);
    orow[lane] = pk;
    v = a1l + b2; x0 = (v > 0.f) ? v : 0.f;
    v = a1h + b3; x1 = (v > 0.f) ? v : 0.f;
    pk = (unsigned)bfr(x0) | ((unsigned)bfr(x1) << 16);
    orow[64 + lane] = pk;
    v = a2l + b4; x0 = (v > 0.f) ? v : 0.f;
    v = a2h + b5; x1 = (v > 0.f) ? v : 0.f;
    pk = (unsigned)bfr(x0) | ((unsigned)bfr(x1) << 16);
    orow[128 + lane] = pk;
}

// ---- K7: segment-sum pool over contiguous per-graph row ranges ----
__global__ __launch_bounds__(192) void pool_k(const unsigned* __restrict__ outb,
                                              const int* __restrict__ gstart,
                                              float* __restrict__ pooled) {
    int g = blockIdx.x;
    int chunk = blockIdx.y;         // 0..7
    int t = threadIdx.x;            // word 0..191
    int lo = gstart[g], hi = gstart[g + 1];
    float al = 0.f, ah = 0.f;
    for (int r = lo + chunk; r < hi; r += 8) {
        unsigned u = outb[(size_t)r * 192 + t];
        al += bflo(u);
        ah += bfhi(u);
    }
    atomicAdd(&pooled[g * HO + 2 * t], al);
    atomicAdd(&pooled[g * HO + 2 * t + 1], ah);
}

// ---- K8: FC over pooled means ----
__global__ __launch_bounds__(64) void fc_k(const float* __restrict__ pooled,
                                           const int* __restrict__ gstart,
                                           const float* __restrict__ fc_w,
                                           const float* __restrict__ fc_b,
                                           float* __restrict__ out) {
    int g = blockIdx.x;
    int lane = threadIdx.x;
    float a0 = 0.f, a1 = 0.f;
#pragma unroll
    for (int k = 0; k < 6; k++) {
        int c = lane + 64 * k;
        float pv = pooled[g * HO + c];
        a0 += pv * fc_w[c * 2 + 0];
        a1 += pv * fc_w[c * 2 + 1];
    }
#pragma unroll
    for (int off = 32; off > 0; off >>= 1) {
        a0 += __shfl_down(a0, off);
        a1 += __shfl_down(a1, off);
    }
    if (lane == 0) {
        float cnt = fmaxf((float)(gstart[g + 1] - gstart[g]), 1.0f);
        out[g * 2 + 0] = a0 / cnt + fc_b[0];
        out[g * 2 + 1] = a1 / cnt + fc_b[1];
    }
}

extern "C" void kernel_launch(void* const* d_in, const int* in_sizes, int n_in,
                              void* d_out, int out_size, void* d_ws, size_t ws_size,
                              hipStream_t stream) {
    const float* x       = (const float*)d_in[0];
    const int*   ei      = (const int*)d_in[1];
    const int*   batch   = (const int*)d_in[2];
    const float* W       = (const float*)d_in[3];
    const float* att_src = (const float*)d_in[4];
    const float* att_dst = (const float*)d_in[5];
    const float* bias    = (const float*)d_in[6];
    const float* fc_w    = (const float*)d_in[7];
    const float* fc_b    = (const float*)d_in[8];
    float* out = (float*)d_out;

    const int N = in_sizes[2];
    const int E = in_sizes[1] / 2;
    const int ET = E + N;

    // bump allocator over d_ws (total ~83 MB)
    char* p = (char*)d_ws;
    auto alloc = [&](size_t bytes) -> char* {
        char* r = p;
        p += (bytes + 255) & ~(size_t)255;
        return r;
    };
    short*    wbt    = (short*)alloc((size_t)HO * F_IN * 2);    // 192 KB
    unsigned* hb     = (unsigned*)alloc((size_t)N * 192 * 4);   // 38.4 MB
    unsigned* outb   = (unsigned*)alloc((size_t)N * 192 * 4);   // 38.4 MB
    float*    a_src  = (float*)alloc((size_t)N * 3 * 4);
    float*    a_dst  = (float*)alloc((size_t)N * 3 * 4);
    char*     zstart = p;
    int*      count  = (int*)alloc((size_t)N * 4);              // zeroed
    float*    pooled = (float*)alloc((size_t)NGRAPH * HO * 4);  // zeroed
    size_t    zbytes = (size_t)(p - zstart);
    int*      offsets = (int*)alloc((size_t)N * 4);
    int*      cursor  = (int*)alloc((size_t)N * 4);
    int*      bsums   = (int*)alloc(4096);
    int*      gstart  = (int*)alloc(1024);
    int*      csr_src = (int*)alloc((size_t)ET * 4);            // 3.4 MB

    hipMemsetAsync(zstart, 0, zbytes, stream);

    conv_wT<<<HO, 256, 0, stream>>>(W, wbt);
    gemm_att<<<(N + 63) / 64, 256, 0, stream>>>(x, wbt, att_src, att_dst,
                                                hb, a_src, a_dst, N);
    count_k<<<(ET + 255) / 256, 256, 0, stream>>>(ei, count, E, N);
    int NB = (N + 255) / 256;
    scan_a<<<NB, 256, 0, stream>>>(count, offsets, bsums, N);
    scan_b<<<1, 256, 0, stream>>>(bsums, NB);
    scan_c<<<NB, 256, 0, stream>>>(offsets, bsums, cursor, N);
    scatter_k<<<(ET + 255) / 256, 256, 0, stream>>>(ei, cursor, csr_src, E, N);
    graph_starts_k<<<1, 128, 0, stream>>>(batch, N, gstart);
    aggregate_k<<<(N + 3) / 4, 256, 0, stream>>>(hb, csr_src, offsets, count,
                                                 a_src, a_dst, bias, outb, N);
    dim3 pg(NGRAPH, 8);
    pool_k<<<pg, 192, 0, stream>>>(outb, gstart, pooled);
    fc_k<<<NGRAPH, 64, 0, stream>>>(pooled, gstart, fc_w, fc_b, out);

    (void)n_in; (void)out_size; (void)ws_size;
}